// Round 1
// baseline (404.114 us; speedup 1.0000x reference)
//
#include <hip/hip_runtime.h>
#include <cmath>

#define B_      32
#define N_      4096
#define D_      512
#define D4      (D_/4)        // 128 float4 per row
#define NCHUNK  32
#define ROWS    (N_/NCHUNK)   // 128 rows per chunk == blockDim
#define IN_DIM  1541          // 3*D + 5
#define NEG_SENT (-1.0e8f)

// ---------------- Kernel 1: per-(batch,chunk) partial sum/sumsq/max ----------
__global__ __launch_bounds__(128) void stats_partial_kernel(
    const float* __restrict__ x, const float* __restrict__ mask,
    float4* __restrict__ psum, float4* __restrict__ psq,
    float4* __restrict__ pmax, float* __restrict__ pcnt)
{
    __shared__ int sidx[ROWS];
    __shared__ int scount;
    const int t = threadIdx.x;      // 0..127, owns d = 4t..4t+3
    const int c = blockIdx.x;       // N-chunk
    const int b = blockIdx.y;       // batch

    if (t == 0) scount = 0;
    __syncthreads();
    {   // compact valid row indices (order irrelevant for sum/max)
        const int n = c * ROWS + t;
        const float mv = mask[b * N_ + n];
        if (mv > NEG_SENT) { int p = atomicAdd(&scount, 1); sidx[p] = n; }
    }
    __syncthreads();
    const int m = scount;

    const float4* __restrict__ xb = (const float4*)x + (size_t)b * N_ * D4 + t;

    const float NINF = -__builtin_inff();
    float4 s0 = {0,0,0,0}, s1 = s0, s2 = s0, s3 = s0;
    float4 q0 = s0, q1 = s0, q2 = s0, q3 = s0;
    float4 m0 = {NINF,NINF,NINF,NINF}, m1 = m0, m2 = m0, m3 = m0;

#define ACC(S,Q,M,V) \
    S.x += V.x; S.y += V.y; S.z += V.z; S.w += V.w; \
    Q.x = fmaf(V.x,V.x,Q.x); Q.y = fmaf(V.y,V.y,Q.y); \
    Q.z = fmaf(V.z,V.z,Q.z); Q.w = fmaf(V.w,V.w,Q.w); \
    M.x = fmaxf(M.x,V.x); M.y = fmaxf(M.y,V.y); \
    M.z = fmaxf(M.z,V.z); M.w = fmaxf(M.w,V.w);

    int i = 0;
    for (; i + 4 <= m; i += 4) {   // 4 independent loads in flight
        const int n0 = sidx[i], n1 = sidx[i+1], n2 = sidx[i+2], n3 = sidx[i+3];
        float4 v0 = xb[(size_t)n0 * D4];
        float4 v1 = xb[(size_t)n1 * D4];
        float4 v2 = xb[(size_t)n2 * D4];
        float4 v3 = xb[(size_t)n3 * D4];
        ACC(s0,q0,m0,v0); ACC(s1,q1,m1,v1); ACC(s2,q2,m2,v2); ACC(s3,q3,m3,v3);
    }
    for (; i < m; ++i) {
        float4 v = xb[(size_t)sidx[i] * D4];
        ACC(s0,q0,m0,v);
    }
#undef ACC
    // merge the 4 accumulator sets
    s0.x += s1.x+s2.x+s3.x; s0.y += s1.y+s2.y+s3.y;
    s0.z += s1.z+s2.z+s3.z; s0.w += s1.w+s2.w+s3.w;
    q0.x += q1.x+q2.x+q3.x; q0.y += q1.y+q2.y+q3.y;
    q0.z += q1.z+q2.z+q3.z; q0.w += q1.w+q2.w+q3.w;
    m0.x = fmaxf(fmaxf(m0.x,m1.x), fmaxf(m2.x,m3.x));
    m0.y = fmaxf(fmaxf(m0.y,m1.y), fmaxf(m2.y,m3.y));
    m0.z = fmaxf(fmaxf(m0.z,m1.z), fmaxf(m2.z,m3.z));
    m0.w = fmaxf(fmaxf(m0.w,m1.w), fmaxf(m2.w,m3.w));

    const size_t idx = ((size_t)(b * NCHUNK + c)) * D4 + t;
    psum[idx] = s0; psq[idx] = q0; pmax[idx] = m0;
    if (t == 0) pcnt[b * NCHUNK + c] = (float)m;
}

// ---------------- Kernel 2: combine partials, build g, run MLP --------------
__global__ __launch_bounds__(128) void mlp_kernel(
    const float4* __restrict__ psum, const float4* __restrict__ psq,
    const float4* __restrict__ pmax, const float* __restrict__ pcnt,
    const float* __restrict__ W1, const float* __restrict__ b1,
    const float* __restrict__ W2, const float* __restrict__ b2,
    const float* __restrict__ W3, const float* __restrict__ b3,
    float* __restrict__ scores)
{
    __shared__ float g[IN_DIM];
    __shared__ float h1[64];
    __shared__ float h2[32];
    const int t = threadIdx.x;     // 0..127
    const int b = blockIdx.x;

    const float NINF = -__builtin_inff();
    float4 s = {0,0,0,0}, q = {0,0,0,0};
    float4 mx = {NINF,NINF,NINF,NINF};
    float cnt = 0.f;
    for (int c = 0; c < NCHUNK; ++c) {
        const size_t idx = ((size_t)(b * NCHUNK + c)) * D4 + t;
        float4 a = psum[idx], u = psq[idx], w = pmax[idx];
        s.x += a.x; s.y += a.y; s.z += a.z; s.w += a.w;
        q.x += u.x; q.y += u.y; q.z += u.z; q.w += u.w;
        mx.x = fmaxf(mx.x,w.x); mx.y = fmaxf(mx.y,w.y);
        mx.z = fmaxf(mx.z,w.z); mx.w = fmaxf(mx.w,w.w);
        cnt += pcnt[b * NCHUNK + c];
    }
    const bool  has = cnt > 0.f;
    const float inv = 1.f / fmaxf(cnt, 1.f);
    const float dn  = 1.f / fmaxf(cnt - 1.f, 1.f);

    float sa[4] = {s.x,s.y,s.z,s.w};
    float qa[4] = {q.x,q.y,q.z,q.w};
    float ma[4] = {mx.x,mx.y,mx.z,mx.w};
    #pragma unroll
    for (int k = 0; k < 4; ++k) {
        const int d = 4*t + k;
        const float mn = has ? sa[k] * inv : 0.f;
        const float vv = fmaxf((qa[k] - cnt * mn * mn) * dn, 0.f);
        g[d]         = mn;
        g[D_ + d]    = has ? ma[k] : 0.f;
        g[2*D_ + d]  = has ? sqrtf(vv) : 0.f;
    }
    if (t == 0) {
        g[3*D_ + 0] = logf(cnt + 1.f) * 0.2f;
        g[3*D_ + 1] = 0.1f;
        g[3*D_ + 2] = 0.2f;
        g[3*D_ + 3] = 4.0f;
        g[3*D_ + 4] = 0.1f;
    }
    __syncthreads();

    if (t < 64) {   // layer 1: 1541 -> 64 ; W1 row-major (IN_DIM,64), coalesced over t
        float a0 = b1[t], a1 = 0.f, a2 = 0.f, a3 = 0.f;
        int i = 0;
        for (; i + 4 <= IN_DIM; i += 4) {
            a0 = fmaf(g[i  ], W1[(i  )*64 + t], a0);
            a1 = fmaf(g[i+1], W1[(i+1)*64 + t], a1);
            a2 = fmaf(g[i+2], W1[(i+2)*64 + t], a2);
            a3 = fmaf(g[i+3], W1[(i+3)*64 + t], a3);
        }
        for (; i < IN_DIM; ++i) a0 = fmaf(g[i], W1[i*64 + t], a0);
        h1[t] = fmaxf((a0 + a1) + (a2 + a3), 0.f);
    }
    __syncthreads();

    if (t < 32) {   // layer 2: 64 -> 32
        float a = b2[t];
        #pragma unroll
        for (int i = 0; i < 64; ++i) a = fmaf(h1[i], W2[i*32 + t], a);
        h2[t] = fmaxf(a, 0.f);
    }
    __syncthreads();

    if (t == 0) {   // layer 3: 32 -> 1, sigmoid
        float a = b3[0];
        #pragma unroll
        for (int i = 0; i < 32; ++i) a = fmaf(h2[i], W3[i], a);
        scores[b] = 1.f / (1.f + expf(-a));
    }
}

// ---------------- Kernel 3: reduce scores -> (num_clusters, score_mean) -----
__global__ __launch_bounds__(64) void final_kernel(
    const float* __restrict__ scores, float* __restrict__ out)
{
    const int t = threadIdx.x;
    float sc = (t < B_) ? scores[t] : 0.f;
    float r  = (t < B_) ? rintf(3.f + sc * 47.f) : 0.f;  // rintf == round-half-even == jnp.round
    #pragma unroll
    for (int off = 32; off > 0; off >>= 1) {
        sc += __shfl_down(sc, off);
        r  += __shfl_down(r,  off);
    }
    if (t == 0) {
        const float mean_r = r * (1.f / 32.f);   // exact: sum of ints / 2^5
        int nc = (int)mean_r;                    // astype(int32): truncate toward zero
        nc = nc < 3 ? 3 : (nc > 50 ? 50 : nc);
        out[0] = (float)nc;
        out[1] = sc * (1.f / 32.f);
    }
}

extern "C" void kernel_launch(void* const* d_in, const int* in_sizes, int n_in,
                              void* d_out, int out_size, void* d_ws, size_t ws_size,
                              hipStream_t stream)
{
    const float* x    = (const float*)d_in[0];
    const float* mask = (const float*)d_in[1];
    const float* W1   = (const float*)d_in[2];
    const float* b1   = (const float*)d_in[3];
    const float* W2   = (const float*)d_in[4];
    const float* b2   = (const float*)d_in[5];
    const float* W3   = (const float*)d_in[6];
    const float* b3   = (const float*)d_in[7];
    float* out = (float*)d_out;

    // workspace layout: psum | psq | pmax (each B*NCHUNK*D4 float4) | pcnt | scores
    const size_t PCOUNT = (size_t)B_ * NCHUNK * D4;   // 131072 float4 per array
    float4* psum = (float4*)d_ws;
    float4* psq  = psum + PCOUNT;
    float4* pmax = psq  + PCOUNT;
    float*  pcnt = (float*)(pmax + PCOUNT);           // B_*NCHUNK floats
    float*  scores = pcnt + (size_t)B_ * NCHUNK;      // B_ floats

    dim3 gridA(NCHUNK, B_);
    stats_partial_kernel<<<gridA, 128, 0, stream>>>(x, mask, psum, psq, pmax, pcnt);
    mlp_kernel<<<B_, 128, 0, stream>>>(psum, psq, pmax, pcnt,
                                       W1, b1, W2, b2, W3, b3, scores);
    final_kernel<<<1, 64, 0, stream>>>(scores, out);
}